// Round 3
// baseline (1239.947 us; speedup 1.0000x reference)
//
#include <hip/hip_runtime.h>
#include <math.h>

#define NPTS (8192 * 128)
#define NRAYS 8192
#define TS (1u << 19)

__global__ __launch_bounds__(256)
void nerf_fwd(const float* __restrict__ X,
              const float* __restrict__ D,
              const float* __restrict__ tables,
              const float* __restrict__ W1, const float* __restrict__ b1,
              const float* __restrict__ W2, const float* __restrict__ b2,
              const float* __restrict__ Wc1, const float* __restrict__ bc1,
              const float* __restrict__ Wc2, const float* __restrict__ bc2,
              const float* __restrict__ Wc3, const float* __restrict__ bc3,
              float* __restrict__ out)
{
    const int p = blockIdx.x * blockDim.x + threadIdx.x;
    if (p >= NPTS) return;

    const float x = X[3 * p + 0];
    const float y = X[3 * p + 1];
    const float z = X[3 * p + 2];

    // res_l = floor(16 * 2^(l/3))
    const float res[16] = {16.f, 20.f, 25.f, 32.f, 40.f, 50.f, 64.f, 80.f,
                           101.f, 128.f, 161.f, 203.f, 256.f, 322.f, 406.f, 512.f};

    float enc[32];
    #pragma unroll
    for (int l = 0; l < 16; ++l) {
        const float r = res[l];
        const float px = x * r, py = y * r, pz = z * r;
        const float fx = floorf(px), fy = floorf(py), fz = floorf(pz);
        const float wx = px - fx, wy = py - fy, wz = pz - fz;
        const uint32_t ix = (uint32_t)fx, iy = (uint32_t)fy, iz = (uint32_t)fz;
        uint32_t hx[2], hy[2], hz[2];
        hx[0] = ix;                     hx[1] = ix + 1u;
        hy[0] = iy * 2654435761u;       hy[1] = (iy + 1u) * 2654435761u;
        hz[0] = iz * 805459861u;        hz[1] = (iz + 1u) * 805459861u;
        float wxs[2], wys[2], wzs[2];
        wxs[0] = 1.f - wx; wxs[1] = wx;
        wys[0] = 1.f - wy; wys[1] = wy;
        wzs[0] = 1.f - wz; wzs[1] = wz;
        const float* tb = tables + (size_t)l * (size_t)TS * 2u;
        float e0 = 0.f, e1 = 0.f;
        #pragma unroll
        for (int c = 0; c < 8; ++c) {
            const int bi = (c >> 2) & 1, bj = (c >> 1) & 1, bk = c & 1;
            const uint32_t idx = (hx[bi] ^ hy[bj] ^ hz[bk]) & (TS - 1u);
            const float2 f = *reinterpret_cast<const float2*>(tb + 2u * (size_t)idx);
            const float w = wxs[bi] * wys[bj] * wzs[bk];
            e0 = fmaf(w, f.x, e0);
            e1 = fmaf(w, f.y, e1);
        }
        enc[2 * l + 0] = e0;
        enc[2 * l + 1] = e1;
    }

    // h1 = relu(enc @ W1.T + b1)   W1:(64,32)
    float h1[64];
    #pragma unroll
    for (int j = 0; j < 64; ++j) {
        float s = b1[j];
        #pragma unroll
        for (int k = 0; k < 32; ++k) s = fmaf(enc[k], W1[j * 32 + k], s);
        h1[j] = fmaxf(s, 0.f);
    }

    // h2 = sigmoid(h1 @ W2.T + b2)   W2:(16,64)
    float h2[16];
    #pragma unroll
    for (int j = 0; j < 16; ++j) {
        float s = b2[j];
        #pragma unroll
        for (int k = 0; k < 64; ++k) s = fmaf(h1[k], W2[j * 64 + k], s);
        h2[j] = 1.f / (1.f + __expf(-s));
    }

    const float density = __expf(fminf(fmaxf(h2[0], -15.f), 15.f));

    // colour-branch input: [geo(15), direnc(24)]
    float cin[39];
    #pragma unroll
    for (int m = 0; m < 15; ++m) cin[m] = h2[m + 1];

    {
        const int ray = p & (NRAYS - 1);
        const float dx = D[3 * ray + 0];
        const float dy = D[3 * ray + 1];
        const float dz = D[3 * ray + 2];
        const float PI = 3.14159265358979323846f;
        #pragma unroll
        for (int i = 0; i < 4; ++i) {
            const float sc = (float)(1 << i) * PI;
            float s0, c0, s1, c1, s2, c2;
            __sincosf(sc * dx, &s0, &c0);
            __sincosf(sc * dy, &s1, &c1);
            __sincosf(sc * dz, &s2, &c2);
            cin[15 + i * 6 + 0] = s0;
            cin[15 + i * 6 + 1] = s1;
            cin[15 + i * 6 + 2] = s2;
            cin[15 + i * 6 + 3] = c0;
            cin[15 + i * 6 + 4] = c1;
            cin[15 + i * 6 + 5] = c2;
        }
    }

    // c1 = relu(cin @ Wc1.T + bc1)   Wc1:(64,39)
    float c1a[64];
    #pragma unroll
    for (int j = 0; j < 64; ++j) {
        float s = bc1[j];
        #pragma unroll
        for (int k = 0; k < 39; ++k) s = fmaf(cin[k], Wc1[j * 39 + k], s);
        c1a[j] = fmaxf(s, 0.f);
    }

    // c2 = relu(c1 @ Wc2.T + bc2)   Wc2:(64,64)
    float c2a[64];
    #pragma unroll
    for (int j = 0; j < 64; ++j) {
        float s = bc2[j];
        #pragma unroll
        for (int k = 0; k < 64; ++k) s = fmaf(c1a[k], Wc2[j * 64 + k], s);
        c2a[j] = fmaxf(s, 0.f);
    }

    // colour = sigmoid(c2 @ Wc3.T + bc3)   Wc3:(3,64)
    float col[3];
    #pragma unroll
    for (int j = 0; j < 3; ++j) {
        float s = bc3[j];
        #pragma unroll
        for (int k = 0; k < 64; ++k) s = fmaf(c2a[k], Wc3[j * 64 + k], s);
        col[j] = 1.f / (1.f + __expf(-s));
    }

    out[p] = density;
    float* outc = out + NPTS;
    outc[3 * p + 0] = col[0];
    outc[3 * p + 1] = col[1];
    outc[3 * p + 2] = col[2];
}

extern "C" void kernel_launch(void* const* d_in, const int* in_sizes, int n_in,
                              void* d_out, int out_size, void* d_ws, size_t ws_size,
                              hipStream_t stream) {
    const float* X   = (const float*)d_in[0];
    const float* D   = (const float*)d_in[1];
    const float* tb  = (const float*)d_in[2];
    const float* W1  = (const float*)d_in[3];
    const float* b1  = (const float*)d_in[4];
    const float* W2  = (const float*)d_in[5];
    const float* b2  = (const float*)d_in[6];
    const float* Wc1 = (const float*)d_in[7];
    const float* bc1 = (const float*)d_in[8];
    const float* Wc2 = (const float*)d_in[9];
    const float* bc2 = (const float*)d_in[10];
    const float* Wc3 = (const float*)d_in[11];
    const float* bc3 = (const float*)d_in[12];
    float* out = (float*)d_out;

    const int block = 256;
    const int grid = (NPTS + block - 1) / block;
    nerf_fwd<<<grid, block, 0, stream>>>(X, D, tb, W1, b1, W2, b2,
                                         Wc1, bc1, Wc2, bc2, Wc3, bc3, out);
}

// Round 4
// 1009.670 us; speedup vs baseline: 1.2281x; 1.2281x over previous
//
#include <hip/hip_runtime.h>
#include <math.h>

#define NPTS (8192 * 128)
#define NRAYS 8192
#define TS (1u << 19)
#define CHUNKS (NPTS / 256)          // 4096 blocks per level
#define ENC_WS_BYTES ((size_t)16 * NPTS * 2 * sizeof(float))   // 128 MB

__constant__ float c_res[16] = {16.f, 20.f, 25.f, 32.f, 40.f, 50.f, 64.f, 80.f,
                                101.f, 128.f, 161.f, 203.f, 256.f, 322.f, 406.f, 512.f};

// ---------------- split path: encode (thread per point-level) ----------------
__global__ __launch_bounds__(256)
void encode_kernel(const float* __restrict__ X,
                   const float* __restrict__ tables,
                   float* __restrict__ enc /* [16][NPTS][2] */)
{
    const int bid = blockIdx.x;
    const int l = bid >> 12;                 // / CHUNKS
    const int p = ((bid & (CHUNKS - 1)) << 8) + threadIdx.x;

    const float x = X[3 * p + 0];
    const float y = X[3 * p + 1];
    const float z = X[3 * p + 2];

    const float r = c_res[l];
    const float px = x * r, py = y * r, pz = z * r;
    const float fx = floorf(px), fy = floorf(py), fz = floorf(pz);
    const float wx = px - fx, wy = py - fy, wz = pz - fz;
    const uint32_t ix = (uint32_t)fx, iy = (uint32_t)fy, iz = (uint32_t)fz;

    uint32_t hx[2], hy[2], hz[2];
    hx[0] = ix;                 hx[1] = ix + 1u;
    hy[0] = iy * 2654435761u;   hy[1] = (iy + 1u) * 2654435761u;
    hz[0] = iz * 805459861u;    hz[1] = (iz + 1u) * 805459861u;
    float wxs[2], wys[2], wzs[2];
    wxs[0] = 1.f - wx; wxs[1] = wx;
    wys[0] = 1.f - wy; wys[1] = wy;
    wzs[0] = 1.f - wz; wzs[1] = wz;

    const float* tb = tables + (size_t)l * (size_t)TS * 2u;
    float e0 = 0.f, e1 = 0.f;
    #pragma unroll
    for (int c = 0; c < 8; ++c) {
        const int bi = (c >> 2) & 1, bj = (c >> 1) & 1, bk = c & 1;
        const uint32_t idx = (hx[bi] ^ hy[bj] ^ hz[bk]) & (TS - 1u);
        const float2 f = *reinterpret_cast<const float2*>(tb + 2u * (size_t)idx);
        const float w = wxs[bi] * wys[bj] * wzs[bk];
        e0 = fmaf(w, f.x, e0);
        e1 = fmaf(w, f.y, e1);
    }
    float2 e; e.x = e0; e.y = e1;
    reinterpret_cast<float2*>(enc)[(size_t)l * NPTS + p] = e;
}

// ---------------- split path: MLP ----------------
__global__ __launch_bounds__(256)
void mlp_kernel(const float* __restrict__ enc,
                const float* __restrict__ D,
                const float* __restrict__ W1, const float* __restrict__ b1,
                const float* __restrict__ W2, const float* __restrict__ b2,
                const float* __restrict__ Wc1, const float* __restrict__ bc1,
                const float* __restrict__ Wc2, const float* __restrict__ bc2,
                const float* __restrict__ Wc3, const float* __restrict__ bc3,
                float* __restrict__ out)
{
    const int p = blockIdx.x * blockDim.x + threadIdx.x;

    float encr[32];
    const float2* enc2 = reinterpret_cast<const float2*>(enc);
    #pragma unroll
    for (int l = 0; l < 16; ++l) {
        const float2 e = enc2[(size_t)l * NPTS + p];
        encr[2 * l + 0] = e.x;
        encr[2 * l + 1] = e.y;
    }

    float h1[64];
    #pragma unroll
    for (int j = 0; j < 64; ++j) {
        float s = b1[j];
        #pragma unroll
        for (int k = 0; k < 32; ++k) s = fmaf(encr[k], W1[j * 32 + k], s);
        h1[j] = fmaxf(s, 0.f);
    }

    float h2[16];
    #pragma unroll
    for (int j = 0; j < 16; ++j) {
        float s = b2[j];
        #pragma unroll
        for (int k = 0; k < 64; ++k) s = fmaf(h1[k], W2[j * 64 + k], s);
        h2[j] = 1.f / (1.f + __expf(-s));
    }

    const float density = __expf(fminf(fmaxf(h2[0], -15.f), 15.f));

    float cin[39];
    #pragma unroll
    for (int m = 0; m < 15; ++m) cin[m] = h2[m + 1];

    {
        const int ray = p & (NRAYS - 1);
        const float dx = D[3 * ray + 0];
        const float dy = D[3 * ray + 1];
        const float dz = D[3 * ray + 2];
        const float PI = 3.14159265358979323846f;
        #pragma unroll
        for (int i = 0; i < 4; ++i) {
            const float sc = (float)(1 << i) * PI;
            float s0, c0, s1, c1, s2, c2;
            __sincosf(sc * dx, &s0, &c0);
            __sincosf(sc * dy, &s1, &c1);
            __sincosf(sc * dz, &s2, &c2);
            cin[15 + i * 6 + 0] = s0;
            cin[15 + i * 6 + 1] = s1;
            cin[15 + i * 6 + 2] = s2;
            cin[15 + i * 6 + 3] = c0;
            cin[15 + i * 6 + 4] = c1;
            cin[15 + i * 6 + 5] = c2;
        }
    }

    float c1a[64];
    #pragma unroll
    for (int j = 0; j < 64; ++j) {
        float s = bc1[j];
        #pragma unroll
        for (int k = 0; k < 39; ++k) s = fmaf(cin[k], Wc1[j * 39 + k], s);
        c1a[j] = fmaxf(s, 0.f);
    }

    float c2a[64];
    #pragma unroll
    for (int j = 0; j < 64; ++j) {
        float s = bc2[j];
        #pragma unroll
        for (int k = 0; k < 64; ++k) s = fmaf(c1a[k], Wc2[j * 64 + k], s);
        c2a[j] = fmaxf(s, 0.f);
    }

    float col[3];
    #pragma unroll
    for (int j = 0; j < 3; ++j) {
        float s = bc3[j];
        #pragma unroll
        for (int k = 0; k < 64; ++k) s = fmaf(c2a[k], Wc3[j * 64 + k], s);
        col[j] = 1.f / (1.f + __expf(-s));
    }

    out[p] = density;
    float* outc = out + NPTS;
    outc[3 * p + 0] = col[0];
    outc[3 * p + 1] = col[1];
    outc[3 * p + 2] = col[2];
}

// ---------------- fallback: fused kernel (proven, round-3) ----------------
__global__ __launch_bounds__(256)
void nerf_fwd(const float* __restrict__ X,
              const float* __restrict__ D,
              const float* __restrict__ tables,
              const float* __restrict__ W1, const float* __restrict__ b1,
              const float* __restrict__ W2, const float* __restrict__ b2,
              const float* __restrict__ Wc1, const float* __restrict__ bc1,
              const float* __restrict__ Wc2, const float* __restrict__ bc2,
              const float* __restrict__ Wc3, const float* __restrict__ bc3,
              float* __restrict__ out)
{
    const int p = blockIdx.x * blockDim.x + threadIdx.x;
    if (p >= NPTS) return;

    const float x = X[3 * p + 0];
    const float y = X[3 * p + 1];
    const float z = X[3 * p + 2];

    float enc[32];
    #pragma unroll
    for (int l = 0; l < 16; ++l) {
        const float r = c_res[l];
        const float px = x * r, py = y * r, pz = z * r;
        const float fx = floorf(px), fy = floorf(py), fz = floorf(pz);
        const float wx = px - fx, wy = py - fy, wz = pz - fz;
        const uint32_t ix = (uint32_t)fx, iy = (uint32_t)fy, iz = (uint32_t)fz;
        uint32_t hx[2], hy[2], hz[2];
        hx[0] = ix;                 hx[1] = ix + 1u;
        hy[0] = iy * 2654435761u;   hy[1] = (iy + 1u) * 2654435761u;
        hz[0] = iz * 805459861u;    hz[1] = (iz + 1u) * 805459861u;
        float wxs[2], wys[2], wzs[2];
        wxs[0] = 1.f - wx; wxs[1] = wx;
        wys[0] = 1.f - wy; wys[1] = wy;
        wzs[0] = 1.f - wz; wzs[1] = wz;
        const float* tb = tables + (size_t)l * (size_t)TS * 2u;
        float e0 = 0.f, e1 = 0.f;
        #pragma unroll
        for (int c = 0; c < 8; ++c) {
            const int bi = (c >> 2) & 1, bj = (c >> 1) & 1, bk = c & 1;
            const uint32_t idx = (hx[bi] ^ hy[bj] ^ hz[bk]) & (TS - 1u);
            const float2 f = *reinterpret_cast<const float2*>(tb + 2u * (size_t)idx);
            const float w = wxs[bi] * wys[bj] * wzs[bk];
            e0 = fmaf(w, f.x, e0);
            e1 = fmaf(w, f.y, e1);
        }
        enc[2 * l + 0] = e0;
        enc[2 * l + 1] = e1;
    }

    float h1[64];
    #pragma unroll
    for (int j = 0; j < 64; ++j) {
        float s = b1[j];
        #pragma unroll
        for (int k = 0; k < 32; ++k) s = fmaf(enc[k], W1[j * 32 + k], s);
        h1[j] = fmaxf(s, 0.f);
    }

    float h2[16];
    #pragma unroll
    for (int j = 0; j < 16; ++j) {
        float s = b2[j];
        #pragma unroll
        for (int k = 0; k < 64; ++k) s = fmaf(h1[k], W2[j * 64 + k], s);
        h2[j] = 1.f / (1.f + __expf(-s));
    }

    const float density = __expf(fminf(fmaxf(h2[0], -15.f), 15.f));

    float cin[39];
    #pragma unroll
    for (int m = 0; m < 15; ++m) cin[m] = h2[m + 1];

    {
        const int ray = p & (NRAYS - 1);
        const float dx = D[3 * ray + 0];
        const float dy = D[3 * ray + 1];
        const float dz = D[3 * ray + 2];
        const float PI = 3.14159265358979323846f;
        #pragma unroll
        for (int i = 0; i < 4; ++i) {
            const float sc = (float)(1 << i) * PI;
            float s0, c0, s1, c1, s2, c2;
            __sincosf(sc * dx, &s0, &c0);
            __sincosf(sc * dy, &s1, &c1);
            __sincosf(sc * dz, &s2, &c2);
            cin[15 + i * 6 + 0] = s0;
            cin[15 + i * 6 + 1] = s1;
            cin[15 + i * 6 + 2] = s2;
            cin[15 + i * 6 + 3] = c0;
            cin[15 + i * 6 + 4] = c1;
            cin[15 + i * 6 + 5] = c2;
        }
    }

    float c1a[64];
    #pragma unroll
    for (int j = 0; j < 64; ++j) {
        float s = bc1[j];
        #pragma unroll
        for (int k = 0; k < 39; ++k) s = fmaf(cin[k], Wc1[j * 39 + k], s);
        c1a[j] = fmaxf(s, 0.f);
    }

    float c2a[64];
    #pragma unroll
    for (int j = 0; j < 64; ++j) {
        float s = bc2[j];
        #pragma unroll
        for (int k = 0; k < 64; ++k) s = fmaf(c1a[k], Wc2[j * 64 + k], s);
        c2a[j] = fmaxf(s, 0.f);
    }

    float col[3];
    #pragma unroll
    for (int j = 0; j < 3; ++j) {
        float s = bc3[j];
        #pragma unroll
        for (int k = 0; k < 64; ++k) s = fmaf(c2a[k], Wc3[j * 64 + k], s);
        col[j] = 1.f / (1.f + __expf(-s));
    }

    out[p] = density;
    float* outc = out + NPTS;
    outc[3 * p + 0] = col[0];
    outc[3 * p + 1] = col[1];
    outc[3 * p + 2] = col[2];
}

extern "C" void kernel_launch(void* const* d_in, const int* in_sizes, int n_in,
                              void* d_out, int out_size, void* d_ws, size_t ws_size,
                              hipStream_t stream) {
    const float* X   = (const float*)d_in[0];
    const float* D   = (const float*)d_in[1];
    const float* tb  = (const float*)d_in[2];
    const float* W1  = (const float*)d_in[3];
    const float* b1  = (const float*)d_in[4];
    const float* W2  = (const float*)d_in[5];
    const float* b2  = (const float*)d_in[6];
    const float* Wc1 = (const float*)d_in[7];
    const float* bc1 = (const float*)d_in[8];
    const float* Wc2 = (const float*)d_in[9];
    const float* bc2 = (const float*)d_in[10];
    const float* Wc3 = (const float*)d_in[11];
    const float* bc3 = (const float*)d_in[12];
    float* out = (float*)d_out;

    if (ws_size >= ENC_WS_BYTES) {
        float* enc = (float*)d_ws;
        encode_kernel<<<16 * CHUNKS, 256, 0, stream>>>(X, tb, enc);
        mlp_kernel<<<NPTS / 256, 256, 0, stream>>>(enc, D, W1, b1, W2, b2,
                                                   Wc1, bc1, Wc2, bc2, Wc3, bc3, out);
    } else {
        nerf_fwd<<<NPTS / 256, 256, 0, stream>>>(X, D, tb, W1, b1, W2, b2,
                                                 Wc1, bc1, Wc2, bc2, Wc3, bc3, out);
    }
}

// Round 5
// 529.557 us; speedup vs baseline: 2.3415x; 1.9066x over previous
//
#include <hip/hip_runtime.h>
#include <math.h>

#define NPTS (8192 * 128)
#define NRAYS 8192
#define TS (1u << 19)
#define CHUNKS (NPTS / 256)

typedef __attribute__((ext_vector_type(8))) short short8_t;
typedef __attribute__((ext_vector_type(4))) float f32x4;

#define ENC_U32S ((size_t)16 * NPTS)                     // one uint (bf16x2) per (level, point)
#define WTS_USHORTS 12288
#define WS_NEED (ENC_U32S * 4 + (size_t)WTS_USHORTS * 2)

__constant__ float c_res[16] = {16.f, 20.f, 25.f, 32.f, 40.f, 50.f, 64.f, 80.f,
                                101.f, 128.f, 161.f, 203.f, 256.f, 322.f, 406.f, 512.f};

__device__ __forceinline__ ushort f2b(float f) {
    uint u = __float_as_uint(f);
    return (ushort)((u + 0x7FFFu + ((u >> 16) & 1u)) >> 16);   // RNE f32->bf16
}

// ---------------- prep: weights -> bf16 B-fragments in ws ----------------
// Fragment layout per 16x16x32 B-tile: [lane 0..63][j 0..7] bf16,
// B[k][n]: n = nt*16 + (lane&15), k = kt*32 + (lane>>4)*8 + j.
// Offsets (ushort units): L1@0(2048) L2@2048(1024) L3@3072(4096) L4@7168(4096) L5@11264(1024)
__global__ __launch_bounds__(256)
void prep_weights(const float* __restrict__ W1, const float* __restrict__ W2,
                  const float* __restrict__ Wc1, const float* __restrict__ Wc2,
                  const float* __restrict__ Wc3, ushort* __restrict__ wts)
{
    const int e = blockIdx.x * 256 + threadIdx.x;   // 0..12287
    float val = 0.f;
    if (e < 2048) {                                  // L1: W1 (64,32), KT=1 NT=4
        int nt = e >> 9, s = e & 511;
        int lane = s >> 3, j = s & 7, quad = lane >> 4, r = lane & 15;
        int k = quad * 8 + j, n = nt * 16 + r;
        val = W1[n * 32 + k];
    } else if (e < 3072) {                           // L2: W2 (16,64), KT=2 NT=1
        int e2 = e - 2048;
        int kt = e2 >> 9, s = e2 & 511;
        int lane = s >> 3, j = s & 7, quad = lane >> 4, r = lane & 15;
        int k = kt * 32 + quad * 8 + j;
        val = W2[r * 64 + k];
    } else if (e < 7168) {                           // L3: Wc1 (64,39) zero-pad K->64
        int e3 = e - 3072;
        int kt = e3 >> 11, rem = e3 & 2047, nt = rem >> 9, s = rem & 511;
        int lane = s >> 3, j = s & 7, quad = lane >> 4, r = lane & 15;
        int k = kt * 32 + quad * 8 + j, n = nt * 16 + r;
        val = (k < 39) ? Wc1[n * 39 + k] : 0.f;
    } else if (e < 11264) {                          // L4: Wc2 (64,64)
        int e4 = e - 7168;
        int kt = e4 >> 11, rem = e4 & 2047, nt = rem >> 9, s = rem & 511;
        int lane = s >> 3, j = s & 7, quad = lane >> 4, r = lane & 15;
        int k = kt * 32 + quad * 8 + j, n = nt * 16 + r;
        val = Wc2[n * 64 + k];
    } else {                                         // L5: Wc3 (3,64) zero-pad N->16
        int e5 = e - 11264;
        int kt = e5 >> 9, s = e5 & 511;
        int lane = s >> 3, j = s & 7, quad = lane >> 4, r = lane & 15;
        int k = kt * 32 + quad * 8 + j;
        val = (r < 3) ? Wc3[r * 64 + k] : 0.f;
    }
    wts[e] = f2b(val);
}

// ---------------- encode: level-major blocks, bf16x2 out [l][NPTS] ----------------
__global__ __launch_bounds__(256)
void encode_kernel(const float* __restrict__ X,
                   const float* __restrict__ tables,
                   uint* __restrict__ enc)
{
    const int bid = blockIdx.x;
    const int l = bid >> 12;                 // / CHUNKS
    const int p = ((bid & (CHUNKS - 1)) << 8) + threadIdx.x;

    const float x = X[3 * p + 0];
    const float y = X[3 * p + 1];
    const float z = X[3 * p + 2];

    const float r = c_res[l];
    const float px = x * r, py = y * r, pz = z * r;
    const float fx = floorf(px), fy = floorf(py), fz = floorf(pz);
    const float wx = px - fx, wy = py - fy, wz = pz - fz;
    const uint32_t ix = (uint32_t)fx, iy = (uint32_t)fy, iz = (uint32_t)fz;

    uint32_t hx[2], hy[2], hz[2];
    hx[0] = ix;                 hx[1] = ix + 1u;
    hy[0] = iy * 2654435761u;   hy[1] = (iy + 1u) * 2654435761u;
    hz[0] = iz * 805459861u;    hz[1] = (iz + 1u) * 805459861u;
    float wxs[2], wys[2], wzs[2];
    wxs[0] = 1.f - wx; wxs[1] = wx;
    wys[0] = 1.f - wy; wys[1] = wy;
    wzs[0] = 1.f - wz; wzs[1] = wz;

    const float* tb = tables + (size_t)l * (size_t)TS * 2u;
    float e0 = 0.f, e1 = 0.f;
    #pragma unroll
    for (int c = 0; c < 8; ++c) {
        const int bi = (c >> 2) & 1, bj = (c >> 1) & 1, bk = c & 1;
        const uint32_t idx = (hx[bi] ^ hy[bj] ^ hz[bk]) & (TS - 1u);
        const float2 f = *reinterpret_cast<const float2*>(tb + 2u * (size_t)idx);
        const float w = wxs[bi] * wys[bj] * wzs[bk];
        e0 = fmaf(w, f.x, e0);
        e1 = fmaf(w, f.y, e1);
    }
    enc[(size_t)l * NPTS + p] = (uint)f2b(e0) | ((uint)f2b(e1) << 16);
}

// ---------------- MFMA MLP: wave-private, 64 points/wave ----------------
// LDS per wave: H[64 rows][64 cols] bf16 (8KB, XOR-swizzled), COL[64][4] f32 (1KB), DEN[64] f32 (256B)
#define WV_LDS (8192 + 1024 + 256)

__device__ __forceinline__ ushort* hptr(char* Hc, int row, int col) {
    return (ushort*)(Hc + ((row * 128 + col * 2) ^ ((row & 7) << 4)));
}

__global__ __launch_bounds__(256, 3)
void mlp_mfma(const uint* __restrict__ enc, const float* __restrict__ D,
              const ushort* __restrict__ wts,
              const float* __restrict__ b1, const float* __restrict__ b2,
              const float* __restrict__ bc1, const float* __restrict__ bc2,
              const float* __restrict__ bc3, float* __restrict__ out)
{
    __shared__ __align__(16) char smem[4 * WV_LDS];
    const int tid = threadIdx.x;
    const int wave = tid >> 6, lane = tid & 63;
    const int quad = lane >> 4, r = lane & 15;
    char* Hc = smem + wave * WV_LDS;
    float* COL = (float*)(Hc + 8192);
    float* DEN = (float*)(Hc + 8192 + 1024);
    const int base = blockIdx.x * 256 + wave * 64;

    // ---- L1: A from enc (global), relu -> H ----
    short8_t a1[4];
    #pragma unroll
    for (int mt = 0; mt < 4; ++mt) {
        union { short8_t s; uint u[4]; } au;
        #pragma unroll
        for (int jj = 0; jj < 4; ++jj)
            au.u[jj] = enc[(size_t)(quad * 4 + jj) * NPTS + (size_t)(base + mt * 16 + r)];
        a1[mt] = au.s;
    }
    #pragma unroll
    for (int nt = 0; nt < 4; ++nt) {
        short8_t b = *(const short8_t*)(wts + nt * 512 + lane * 8);
        float bias = b1[nt * 16 + r];
        #pragma unroll
        for (int mt = 0; mt < 4; ++mt) {
            f32x4 acc = {0.f, 0.f, 0.f, 0.f};
            acc = __builtin_amdgcn_mfma_f32_16x16x32_bf16(a1[mt], b, acc, 0, 0, 0);
            #pragma unroll
            for (int g = 0; g < 4; ++g) {
                float v = fmaxf(acc[g] + bias, 0.f);
                *hptr(Hc, mt * 16 + quad * 4 + g, nt * 16 + r) = f2b(v);
            }
        }
    }

    // ---- L2: K=64 N=16, sigmoid; n=0 -> density, n=1..15 -> cin cols 0..14 ----
    f32x4 acc2[4];
    #pragma unroll
    for (int mt = 0; mt < 4; ++mt) acc2[mt] = (f32x4){0.f, 0.f, 0.f, 0.f};
    #pragma unroll
    for (int kt = 0; kt < 2; ++kt) {
        short8_t b = *(const short8_t*)(wts + 2048 + kt * 512 + lane * 8);
        #pragma unroll
        for (int mt = 0; mt < 4; ++mt) {
            int row = mt * 16 + r;
            short8_t a = *(const short8_t*)(Hc + ((row * 128 + kt * 64 + quad * 16) ^ ((row & 7) << 4)));
            acc2[mt] = __builtin_amdgcn_mfma_f32_16x16x32_bf16(a, b, acc2[mt], 0, 0, 0);
        }
    }
    {
        float bias = b2[r];
        #pragma unroll
        for (int mt = 0; mt < 4; ++mt)
        #pragma unroll
        for (int g = 0; g < 4; ++g) {
            float s = acc2[mt][g] + bias;
            float h = 1.f / (1.f + __expf(-s));
            int pl = mt * 16 + quad * 4 + g;
            if (r == 0) DEN[pl] = __expf(fminf(fmaxf(h, -15.f), 15.f));
            else        *hptr(Hc, pl, r - 1) = f2b(h);
        }
    }

    // ---- direnc: each thread fills its own row, cols 15..38 ----
    {
        int ray = (base + lane) & (NRAYS - 1);
        float dx = D[3 * ray], dy = D[3 * ray + 1], dz = D[3 * ray + 2];
        const float PI = 3.14159265358979323846f;
        #pragma unroll
        for (int i = 0; i < 4; ++i) {
            float sc = (float)(1 << i) * PI;
            float s0, c0, s1, c1, s2, c2;
            __sincosf(sc * dx, &s0, &c0);
            __sincosf(sc * dy, &s1, &c1);
            __sincosf(sc * dz, &s2, &c2);
            float vals[6] = {s0, s1, s2, c0, c1, c2};
            #pragma unroll
            for (int o = 0; o < 6; ++o)
                *hptr(Hc, lane, 15 + i * 6 + o) = f2b(vals[o]);
        }
    }
    // cols 39..63 hold stale (finite) h1 values; L3 B rows 39..63 are zero -> contribute 0.

    // ---- L3: K=64 N=64 relu ----
    short8_t a3[4][2];
    #pragma unroll
    for (int mt = 0; mt < 4; ++mt)
    #pragma unroll
    for (int kt = 0; kt < 2; ++kt) {
        int row = mt * 16 + r;
        a3[mt][kt] = *(const short8_t*)(Hc + ((row * 128 + kt * 64 + quad * 16) ^ ((row & 7) << 4)));
    }
    #pragma unroll
    for (int nt = 0; nt < 4; ++nt) {
        short8_t bA = *(const short8_t*)(wts + 3072 + nt * 512 + lane * 8);
        short8_t bB = *(const short8_t*)(wts + 3072 + (4 + nt) * 512 + lane * 8);
        float bias = bc1[nt * 16 + r];
        #pragma unroll
        for (int mt = 0; mt < 4; ++mt) {
            f32x4 acc = {0.f, 0.f, 0.f, 0.f};
            acc = __builtin_amdgcn_mfma_f32_16x16x32_bf16(a3[mt][0], bA, acc, 0, 0, 0);
            acc = __builtin_amdgcn_mfma_f32_16x16x32_bf16(a3[mt][1], bB, acc, 0, 0, 0);
            #pragma unroll
            for (int g = 0; g < 4; ++g) {
                float v = fmaxf(acc[g] + bias, 0.f);
                *hptr(Hc, mt * 16 + quad * 4 + g, nt * 16 + r) = f2b(v);
            }
        }
    }

    // ---- L4: K=64 N=64 relu ----
    short8_t a4[4][2];
    #pragma unroll
    for (int mt = 0; mt < 4; ++mt)
    #pragma unroll
    for (int kt = 0; kt < 2; ++kt) {
        int row = mt * 16 + r;
        a4[mt][kt] = *(const short8_t*)(Hc + ((row * 128 + kt * 64 + quad * 16) ^ ((row & 7) << 4)));
    }
    #pragma unroll
    for (int nt = 0; nt < 4; ++nt) {
        short8_t bA = *(const short8_t*)(wts + 7168 + nt * 512 + lane * 8);
        short8_t bB = *(const short8_t*)(wts + 7168 + (4 + nt) * 512 + lane * 8);
        float bias = bc2[nt * 16 + r];
        #pragma unroll
        for (int mt = 0; mt < 4; ++mt) {
            f32x4 acc = {0.f, 0.f, 0.f, 0.f};
            acc = __builtin_amdgcn_mfma_f32_16x16x32_bf16(a4[mt][0], bA, acc, 0, 0, 0);
            acc = __builtin_amdgcn_mfma_f32_16x16x32_bf16(a4[mt][1], bB, acc, 0, 0, 0);
            #pragma unroll
            for (int g = 0; g < 4; ++g) {
                float v = fmaxf(acc[g] + bias, 0.f);
                *hptr(Hc, mt * 16 + quad * 4 + g, nt * 16 + r) = f2b(v);
            }
        }
    }

    // ---- L5: K=64 N=16(3 used), sigmoid -> COL ----
    short8_t a5[4][2];
    #pragma unroll
    for (int mt = 0; mt < 4; ++mt)
    #pragma unroll
    for (int kt = 0; kt < 2; ++kt) {
        int row = mt * 16 + r;
        a5[mt][kt] = *(const short8_t*)(Hc + ((row * 128 + kt * 64 + quad * 16) ^ ((row & 7) << 4)));
    }
    {
        short8_t b50 = *(const short8_t*)(wts + 11264 + lane * 8);
        short8_t b51 = *(const short8_t*)(wts + 11264 + 512 + lane * 8);
        float bias = (r < 3) ? bc3[r] : 0.f;
        #pragma unroll
        for (int mt = 0; mt < 4; ++mt) {
            f32x4 acc = {0.f, 0.f, 0.f, 0.f};
            acc = __builtin_amdgcn_mfma_f32_16x16x32_bf16(a5[mt][0], b50, acc, 0, 0, 0);
            acc = __builtin_amdgcn_mfma_f32_16x16x32_bf16(a5[mt][1], b51, acc, 0, 0, 0);
            #pragma unroll
            for (int g = 0; g < 4; ++g) {
                if (r < 3) {
                    float v = 1.f / (1.f + __expf(-(acc[g] + bias)));
                    COL[(mt * 16 + quad * 4 + g) * 4 + r] = v;
                }
            }
        }
    }

    // ---- coalesced final stores ----
    float den = DEN[lane];
    float cx = COL[lane * 4 + 0];
    float cy = COL[lane * 4 + 1];
    float cz = COL[lane * 4 + 2];
    out[base + lane] = den;
    float* oc = out + (size_t)NPTS + (size_t)(base + lane) * 3;
    oc[0] = cx; oc[1] = cy; oc[2] = cz;
}

// ---------------- fallback: fused fp32 kernel (round-3, proven) ----------------
__global__ __launch_bounds__(256)
void nerf_fwd(const float* __restrict__ X,
              const float* __restrict__ D,
              const float* __restrict__ tables,
              const float* __restrict__ W1, const float* __restrict__ b1,
              const float* __restrict__ W2, const float* __restrict__ b2,
              const float* __restrict__ Wc1, const float* __restrict__ bc1,
              const float* __restrict__ Wc2, const float* __restrict__ bc2,
              const float* __restrict__ Wc3, const float* __restrict__ bc3,
              float* __restrict__ out)
{
    const int p = blockIdx.x * blockDim.x + threadIdx.x;
    if (p >= NPTS) return;

    const float x = X[3 * p + 0];
    const float y = X[3 * p + 1];
    const float z = X[3 * p + 2];

    float enc[32];
    #pragma unroll
    for (int l = 0; l < 16; ++l) {
        const float r = c_res[l];
        const float px = x * r, py = y * r, pz = z * r;
        const float fx = floorf(px), fy = floorf(py), fz = floorf(pz);
        const float wx = px - fx, wy = py - fy, wz = pz - fz;
        const uint32_t ix = (uint32_t)fx, iy = (uint32_t)fy, iz = (uint32_t)fz;
        uint32_t hx[2], hy[2], hz[2];
        hx[0] = ix;                 hx[1] = ix + 1u;
        hy[0] = iy * 2654435761u;   hy[1] = (iy + 1u) * 2654435761u;
        hz[0] = iz * 805459861u;    hz[1] = (iz + 1u) * 805459861u;
        float wxs[2], wys[2], wzs[2];
        wxs[0] = 1.f - wx; wxs[1] = wx;
        wys[0] = 1.f - wy; wys[1] = wy;
        wzs[0] = 1.f - wz; wzs[1] = wz;
        const float* tb = tables + (size_t)l * (size_t)TS * 2u;
        float e0 = 0.f, e1 = 0.f;
        #pragma unroll
        for (int c = 0; c < 8; ++c) {
            const int bi = (c >> 2) & 1, bj = (c >> 1) & 1, bk = c & 1;
            const uint32_t idx = (hx[bi] ^ hy[bj] ^ hz[bk]) & (TS - 1u);
            const float2 f = *reinterpret_cast<const float2*>(tb + 2u * (size_t)idx);
            const float w = wxs[bi] * wys[bj] * wzs[bk];
            e0 = fmaf(w, f.x, e0);
            e1 = fmaf(w, f.y, e1);
        }
        enc[2 * l + 0] = e0;
        enc[2 * l + 1] = e1;
    }

    float h1[64];
    #pragma unroll
    for (int j = 0; j < 64; ++j) {
        float s = b1[j];
        #pragma unroll
        for (int k = 0; k < 32; ++k) s = fmaf(enc[k], W1[j * 32 + k], s);
        h1[j] = fmaxf(s, 0.f);
    }

    float h2[16];
    #pragma unroll
    for (int j = 0; j < 16; ++j) {
        float s = b2[j];
        #pragma unroll
        for (int k = 0; k < 64; ++k) s = fmaf(h1[k], W2[j * 64 + k], s);
        h2[j] = 1.f / (1.f + __expf(-s));
    }

    const float density = __expf(fminf(fmaxf(h2[0], -15.f), 15.f));

    float cin[39];
    #pragma unroll
    for (int m = 0; m < 15; ++m) cin[m] = h2[m + 1];

    {
        const int ray = p & (NRAYS - 1);
        const float dx = D[3 * ray + 0];
        const float dy = D[3 * ray + 1];
        const float dz = D[3 * ray + 2];
        const float PI = 3.14159265358979323846f;
        #pragma unroll
        for (int i = 0; i < 4; ++i) {
            const float sc = (float)(1 << i) * PI;
            float s0, c0, s1, c1, s2, c2;
            __sincosf(sc * dx, &s0, &c0);
            __sincosf(sc * dy, &s1, &c1);
            __sincosf(sc * dz, &s2, &c2);
            cin[15 + i * 6 + 0] = s0;
            cin[15 + i * 6 + 1] = s1;
            cin[15 + i * 6 + 2] = s2;
            cin[15 + i * 6 + 3] = c0;
            cin[15 + i * 6 + 4] = c1;
            cin[15 + i * 6 + 5] = c2;
        }
    }

    float c1a[64];
    #pragma unroll
    for (int j = 0; j < 64; ++j) {
        float s = bc1[j];
        #pragma unroll
        for (int k = 0; k < 39; ++k) s = fmaf(cin[k], Wc1[j * 39 + k], s);
        c1a[j] = fmaxf(s, 0.f);
    }

    float c2a[64];
    #pragma unroll
    for (int j = 0; j < 64; ++j) {
        float s = bc2[j];
        #pragma unroll
        for (int k = 0; k < 64; ++k) s = fmaf(c1a[k], Wc2[j * 64 + k], s);
        c2a[j] = fmaxf(s, 0.f);
    }

    float col[3];
    #pragma unroll
    for (int j = 0; j < 3; ++j) {
        float s = bc3[j];
        #pragma unroll
        for (int k = 0; k < 64; ++k) s = fmaf(c2a[k], Wc3[j * 64 + k], s);
        col[j] = 1.f / (1.f + __expf(-s));
    }

    out[p] = density;
    float* outc = out + NPTS;
    outc[3 * p + 0] = col[0];
    outc[3 * p + 1] = col[1];
    outc[3 * p + 2] = col[2];
}

extern "C" void kernel_launch(void* const* d_in, const int* in_sizes, int n_in,
                              void* d_out, int out_size, void* d_ws, size_t ws_size,
                              hipStream_t stream) {
    const float* X   = (const float*)d_in[0];
    const float* D   = (const float*)d_in[1];
    const float* tb  = (const float*)d_in[2];
    const float* W1  = (const float*)d_in[3];
    const float* b1  = (const float*)d_in[4];
    const float* W2  = (const float*)d_in[5];
    const float* b2  = (const float*)d_in[6];
    const float* Wc1 = (const float*)d_in[7];
    const float* bc1 = (const float*)d_in[8];
    const float* Wc2 = (const float*)d_in[9];
    const float* bc2 = (const float*)d_in[10];
    const float* Wc3 = (const float*)d_in[11];
    const float* bc3 = (const float*)d_in[12];
    float* out = (float*)d_out;

    if (ws_size >= WS_NEED) {
        uint* encb = (uint*)d_ws;
        ushort* wtsb = (ushort*)((char*)d_ws + ENC_U32S * 4);
        prep_weights<<<48, 256, 0, stream>>>(W1, W2, Wc1, Wc2, Wc3, wtsb);
        encode_kernel<<<16 * CHUNKS, 256, 0, stream>>>(X, tb, encb);
        mlp_mfma<<<NPTS / 256, 256, 0, stream>>>(encb, D, wtsb, b1, b2, bc1, bc2, bc3, out);
    } else {
        nerf_fwd<<<NPTS / 256, 256, 0, stream>>>(X, D, tb, W1, b1, W2, b2,
                                                 Wc1, bc1, Wc2, bc2, Wc3, bc3, out);
    }
}